// Round 7
// baseline (14431.371 us; speedup 1.0000x reference)
//
#include <hip/hip_runtime.h>
#include <math.h>

// Round 6 resubmit (infra timeout; source re-reviewed, unchanged).
// Full weight residency (VGPR+LDS) + 4-block same-XCD exchange.
// 256 blocks = 256 CUs. Block (b = blockIdx&63, q = blockIdx>>6) owns neurons
// [64q, 64q+64) of batch b across all 9 matrices = 576 rows of 256 fp16.
// 192 threads x 3 rows: rows tid, tid+192 pinned in VGPRs (64 uint4 = 256
// VGPRs; 3 waves/CU = 1 wave/SIMD -> 512-VGPR budget), row tid+384 in LDS
// (96 KB, [kq][tid] tiling -> lane-consecutive ds_read_b128). Zero per-step
// weight traffic. Per step the 4 sibling blocks exchange their 64-float r
// chunks through r_hist itself (write-once channel, proven in rounds 1-2)
// with per-writer release flags on private 64-B lines (no RMW contention);
// siblings {b,b+64,b+128,b+192} share XCD b%8 under default dispatch (perf
// bonus only -- correctness holds via agent-scope fence/flag protocol).
// Dot math identical to round 5: fp16 weights, split-fp16 r, v_dot2_f32_f16.

#define BATCH 64
#define TT    512
#define NN    256
#define ADIM  8
#define NQ    4               // blocks per batch
#define NTB   192             // threads per block (3 waves)
#define RPB   576             // rows per block: 9 mats x 64 neurons
#define KQ    32              // uint4 (8 fp16-pair) chunks per 256-col row

typedef _Float16 half2_t __attribute__((ext_vector_type(2)));

static __device__ __forceinline__ half2_t u2h(unsigned int u) {
  union { unsigned int u; half2_t h; } c; c.u = u; return c.h;
}

static __device__ __forceinline__ void dot4(uint4 w, uint4 rh, uint4 rl,
                                            float& ah, float& al) {
  ah = __builtin_amdgcn_fdot2(u2h(w.x), u2h(rh.x), ah, false);
  ah = __builtin_amdgcn_fdot2(u2h(w.y), u2h(rh.y), ah, false);
  ah = __builtin_amdgcn_fdot2(u2h(w.z), u2h(rh.z), ah, false);
  ah = __builtin_amdgcn_fdot2(u2h(w.w), u2h(rh.w), ah, false);
  al = __builtin_amdgcn_fdot2(u2h(w.x), u2h(rl.x), al, false);
  al = __builtin_amdgcn_fdot2(u2h(w.y), u2h(rl.y), al, false);
  al = __builtin_amdgcn_fdot2(u2h(w.z), u2h(rl.z), al, false);
  al = __builtin_amdgcn_fdot2(u2h(w.w), u2h(rl.w), al, false);
}

// -------- pre-pass: tiled fp16-pair weights in ws --------
// Linear layout: Wt[(((q*3 + g)*KQ + kq)*NTB + tid], row rr = g*192 + tid,
// (mat, il) = (rr>>6, rr&63), neuron i = q*64 + il, cols [kq*8, kq*8+8).
__global__ __launch_bounds__(256)
void build_wt_kernel(const float* __restrict__ Wo,
                     const float* __restrict__ Wa,
                     const float* __restrict__ J0,
                     uint4* __restrict__ Wt)
{
  const int idx = blockIdx.x * 256 + threadIdx.x;   // 0..73727
  const int tid = idx % NTB;
  const int u   = idx / NTB;        // 0..383
  const int kq  = u & 31;
  const int v   = u >> 5;           // 0..11
  const int g   = v % 3;
  const int q   = v / 3;            // 0..3
  const int rr  = g * NTB + tid;    // 0..575
  const int mat = rr >> 6;
  const int i   = q * 64 + (rr & 63);
  const int c0  = kq * 8;
  float val[8];
  if (mat == 0) {
    #pragma unroll
    for (int j = 0; j < 8; ++j)
      val[j] = J0[i * NN + c0 + j] + 0.1f * Wo[i * NN + c0 + j];  // J0+J1*Wo
  } else {
    const float* src = Wa + ((size_t)(mat - 1) * NN + i) * NN + c0;
    #pragma unroll
    for (int j = 0; j < 8; ++j) val[j] = src[j];
  }
  unsigned int p[4];
  #pragma unroll
  for (int j = 0; j < 4; ++j) {
    _Float16 hl = (_Float16)val[2 * j];       // RNE
    _Float16 hh = (_Float16)val[2 * j + 1];
    unsigned short sl, sh;
    __builtin_memcpy(&sl, &hl, 2);
    __builtin_memcpy(&sh, &hh, 2);
    p[j] = (unsigned int)sl | ((unsigned int)sh << 16);
  }
  Wt[idx] = make_uint4(p[0], p[1], p[2], p[3]);
}

__global__ __launch_bounds__(NTB, 1)
void ring_main_kernel(const float* __restrict__ act,     // [64,512,8]
                      const float* __restrict__ r_init,  // [64,256]
                      const float* __restrict__ Wd7,     // [256,256]
                      const uint4* __restrict__ Wt,
                      float* __restrict__ out,           // r_hist | bump
                      unsigned int* __restrict__ flags)  // [64][4] x 64B lines
{
  __shared__ uint4 wl[KQ * NTB];    // 3rd row-group weights, 96 KB
  __shared__ uint4 rhq[KQ];         // r high fp16 pairs (256 halfs)
  __shared__ uint4 rlq[KQ];         // r residual*2^11 fp16 pairs
  __shared__ float m_s[RPB];        // per-row dots, [mat][il]
  __shared__ float r_f[NN];         // full fp32 r (authoritative)
  __shared__ float cvec[NN], svec[NN];
  __shared__ float at_s[ADIM];
  __shared__ float cs_s[3][2];
  __shared__ float sums_s[3];

  const int tid  = threadIdx.x;
  const int wv   = tid >> 6;
  const int lane = tid & 63;
  const int b    = blockIdx.x & 63;
  const int q    = blockIdx.x >> 6;
  const int i0   = q * 64;

  float* out_r = out;
  float* out_b = out + (size_t)BATCH * TT * NN;
  const float LS = 1.0f / 2048.0f;

  // ---- init ----
  for (int idx = tid; idx < NN; idx += NTB) {
    cvec[idx] = Wd7[idx * NN];          // cos(theta_i)
    svec[idx] = Wd7[idx * NN + 64];     // sin(theta_i)
    const float rv = r_init[b * NN + idx];
    r_f[idx] = rv;
    _Float16 h = (_Float16)rv;
    _Float16 l = (_Float16)((rv - (float)h) * 2048.0f);
    ((_Float16*)rhq)[idx] = h;
    ((_Float16*)rlq)[idx] = l;
  }
  // weights: 2 row-groups to VGPRs, 3rd to LDS
  const uint4* Wq = Wt + (size_t)q * 3 * KQ * NTB;
  uint4 w0[KQ], w1[KQ];
  #pragma unroll
  for (int kq = 0; kq < KQ; ++kq) w0[kq] = Wq[kq * NTB + tid];
  #pragma unroll
  for (int kq = 0; kq < KQ; ++kq) w1[kq] = Wq[(KQ + kq) * NTB + tid];
  for (int kq = 0; kq < KQ; ++kq)
    wl[kq * NTB + tid] = Wq[(2 * KQ + kq) * NTB + tid];
  __syncthreads();
  if (tid == 0) {
    float a = 0.f, c2 = 0.f, c = 0.f;
    for (int j = 0; j < NN; ++j) {
      const float cj = cvec[j], sj = svec[j];
      a += cj * cj; c2 += cj * sj; c += sj * sj;
    }
    sums_s[0] = a; sums_s[1] = c2; sums_s[2] = c;
  }
  __syncthreads();

  for (unsigned int t = 0; t < TT; ++t) {
    if (tid < ADIM) at_s[tid] = act[((size_t)b * TT + t) * ADIM + tid];

    // ---- Phase A: 3 row-dots per thread (2 reg rows + 1 LDS row) ----
    float ah0 = 0.f, al0 = 0.f, ah1 = 0.f, al1 = 0.f, ah2 = 0.f, al2 = 0.f;
    #pragma unroll
    for (int kq = 0; kq < KQ; ++kq) {
      const uint4 rh = rhq[kq];             // uniform b128 broadcast
      const uint4 rl = rlq[kq];
      dot4(w0[kq], rh, rl, ah0, al0);
      dot4(w1[kq], rh, rl, ah1, al1);
      const uint4 wx = wl[kq * NTB + tid];  // lane-consecutive b128
      dot4(wx, rh, rl, ah2, al2);
    }
    m_s[tid]           = ah0 + al0 * LS;
    m_s[tid + NTB]     = ah1 + al1 * LS;
    m_s[tid + 2 * NTB] = ah2 + al2 * LS;
    __syncthreads();                        // S1: m_s, at_s ready

    // ---- Phase B: combine + tanh-leak + publish own chunk ----
    if (tid < 64) {
      const int il = tid;
      float rec = m_s[il];                  // mat 0
      #pragma unroll
      for (int a = 0; a < ADIM; ++a)
        rec += at_s[a] * m_s[(1 + a) * 64 + il];
      const float ro = r_f[i0 + il];
      const float rn = ro + 0.1f * (tanhf(rec) - ro);   // DT/TAU = 0.1
      out_r[((size_t)b * TT + t) * NN + i0 + il] = rn;  // exchange channel
      r_f[i0 + il] = rn;
      _Float16 h = (_Float16)rn;
      _Float16 l = (_Float16)((rn - (float)h) * 2048.0f);
      ((_Float16*)rhq)[i0 + il] = h;
      ((_Float16*)rlq)[i0 + il] = l;
    }
    __threadfence();
    __syncthreads();                        // S2: all stores fenced
    if (tid == 0)
      __hip_atomic_store(&flags[(b * NQ + q) * 16], t + 1u,
                         __ATOMIC_RELEASE, __HIP_MEMORY_SCOPE_AGENT);
    if (tid < NQ - 1) {                     // poll 3 sibling flags
      const int pq = tid < q ? tid : tid + 1;
      while (__hip_atomic_load(&flags[(b * NQ + pq) * 16],
                               __ATOMIC_ACQUIRE, __HIP_MEMORY_SCOPE_AGENT)
             < t + 1u)
        __builtin_amdgcn_s_sleep(1);
    }
    __syncthreads();                        // S3: siblings done
    __threadfence();                        // acquire side

    // ---- pull siblings' 192 floats, rebuild split state ----
    {
      const int gi = tid + (tid >= i0 ? 64 : 0);   // skip own quarter
      const float v = out_r[((size_t)b * TT + t) * NN + gi];
      r_f[gi] = v;
      _Float16 h = (_Float16)v;
      _Float16 l = (_Float16)((v - (float)h) * 2048.0f);
      ((_Float16*)rhq)[gi] = h;
      ((_Float16*)rlq)[gi] = l;
    }
    __syncthreads();                        // S4: full r ready

    // ---- Phase C: C/S reduce + bump for own 64 neurons ----
    {
      float rv = r_f[tid];
      float cp = cvec[tid] * rv, sp = svec[tid] * rv;
      if (tid < 64) {
        const float rv2 = r_f[tid + NTB];
        cp += cvec[tid + NTB] * rv2;
        sp += svec[tid + NTB] * rv2;
      }
      #pragma unroll
      for (int m = 1; m < 64; m <<= 1) {
        cp += __shfl_xor(cp, m);
        sp += __shfl_xor(sp, m);
      }
      if (lane == 0) { cs_s[wv][0] = cp; cs_s[wv][1] = sp; }
    }
    __syncthreads();                        // S5: cs ready
    if (tid < 64) {
      const float C = cs_s[0][0] + cs_s[1][0] + cs_s[2][0];
      const float S = cs_s[0][1] + cs_s[1][1] + cs_s[2][1];
      const float n2 = sums_s[0] * C * C + 2.f * sums_s[1] * C * S
                     + sums_s[2] * S * S;
      out_b[((size_t)b * TT + t) * NN + i0 + tid] =
          (cvec[i0 + tid] * C + svec[i0 + tid] * S) * (1.0f / sqrtf(n2));
    }
    // next Phase A reads rhq/rlq (stable since S4) and writes m_s (last read
    // pre-S2); at_s rewritten at loop top (last read pre-S2). No extra sync.
  }
}

extern "C" void kernel_launch(void* const* d_in, const int* in_sizes, int n_in,
                              void* d_out, int out_size, void* d_ws, size_t ws_size,
                              hipStream_t stream) {
  const float* act    = (const float*)d_in[0];
  const float* r_init = (const float*)d_in[1];
  const float* Wo     = (const float*)d_in[2];
  const float* Wa     = (const float*)d_in[3];
  const float* J0     = (const float*)d_in[4];
  const float* Wd7    = (const float*)d_in[5];
  float* out = (float*)d_out;
  uint4* Wt = (uint4*)d_ws;                         // 73728 uint4 = 1.125 MiB
  unsigned int* flags = (unsigned int*)((char*)d_ws + 73728 * 16);  // 16 KB

  hipMemsetAsync(flags, 0, BATCH * NQ * 16 * sizeof(unsigned int), stream);
  hipLaunchKernelGGL(build_wt_kernel, dim3(288), dim3(256), 0, stream,
                     Wo, Wa, J0, Wt);
  hipLaunchKernelGGL(ring_main_kernel, dim3(BATCH * NQ), dim3(NTB), 0, stream,
                     act, r_init, Wd7, (const uint4*)Wt, out, flags);
}